// Round 3
// baseline (342.467 us; speedup 1.0000x reference)
//
#include <hip/hip_runtime.h>
#include <stdint.h>

// BMM: out[b,m,n] = round(alpha * sum_k a[b,m,k]*b[b,n,k]), int8 x int8 -> int32
// B=64, M=1024, N=1024, K=128.  Inputs arrive int32-expanded; output 256 MB int32.
//
// R7: FUSED single kernel — no prepack pass, no workspace use.
// Rationale: R2..R6 span 4x read traffic, NT vs plain stores, drained vs
// drain-free barriers — all within ±2%.  Conclusion: measured time is
// dominated by fixed harness work (1 GiB poison fill = 167us @6.3TB/s) plus
// a BMM already near its 256 MiB write floor (~45us).  The only controllable
// remainder: (a) the prepack dispatch (~13us + 32 MiB ws round-trip), and
// (b) the possibility that the 1 GiB fill is a conditional ws-poison that
// disappears when d_ws is unused.  Each block now reads its int32 panels
// directly (128 KB/block, L2/L3-absorbed 8x reuse — the R2/R3 pattern that
// tied with prepack) and packs in-register before the swizzled ds_write.
//
// Kept from R5/R6 (verified correct): XOR-swizzled LDS tiles, 4-wave
// 32x32x32_i8 MFMA layout, lgkm-only barriers (no vmcnt drain), 2-round
// 64-row LDS-transpose epilogue with plain dwordx4 stores.

typedef int v4i  __attribute__((ext_vector_type(4)));
typedef int v16i __attribute__((ext_vector_type(16)));

__device__ __forceinline__ int pack4(v4i w) {
    // low bytes of 4 int32 -> one dword of 4 int8 (two's complement)
    return (w.x & 0xFF) | ((w.y & 0xFF) << 8) | ((w.z & 0xFF) << 16) | (w.w << 24);
}

// Raw barrier: lgkm-only wait, NO vmcnt drain (unlike __syncthreads()).
// Correct here: barriers only order LDS producer/consumer phases; global
// stores are never read back.
__device__ __forceinline__ void lgkm_barrier() {
    asm volatile("s_waitcnt lgkmcnt(0)" ::: "memory");
    __builtin_amdgcn_s_barrier();
}

// One 128x128 C-tile per block.  Stage reads int32 panels directly and packs.
__global__ __launch_bounds__(256, 4) void bmm_s8s8_s32_fused(
    const int*   __restrict__ A32,     // [64,1024,128] int32 (int8 values)
    const int*   __restrict__ B32,     // [64,1024,128] int32 (int8 values)
    const float* __restrict__ alpha_p,
    int*         __restrict__ out)     // [64,1024,1024]
{
    __shared__ uint8_t smem[32768];
    uint8_t* Als = smem;               // 16 KB packed A-tile, XOR-swizzled rows
    uint8_t* Bls = smem + 16384;       // 16 KB packed B-tile

    const int tid   = threadIdx.x;
    const int lane  = tid & 63;
    const int wave  = tid >> 6;        // 0..3
    const int half_ = lane >> 5;       // 0..1
    const int lrow  = lane & 31;       // 0..31

    const int bz = blockIdx.z;
    const int m0 = blockIdx.y << 7;
    const int n0 = blockIdx.x << 7;

    const float alpha = *alpha_p;

    // int32 element bases; each 128-row panel is 16384 contiguous ints.
    const int* Ap = A32 + ((size_t)bz * 1024 + (size_t)m0) * 128;
    const int* Bp = B32 + ((size_t)bz * 1024 + (size_t)n0) * 128;

    // ---- Stage: 16384 ints per matrix -> 64 ints (16 granules of 4) per
    //      thread per matrix.  Granule G = t*256+tid covers ints [4G,4G+4):
    //      row m = G>>5, dword-in-row q = G&31.  Pack to one dword, then
    //      swizzled ds_write_b32 consistent with the compute-phase reads:
    //      byte = m*128 + ((q>>2)^(m&7))*16 + (q&3)*4.
    //      Per-instruction: lanes have consecutive G -> 1 KB contiguous
    //      global load, bank-conflict-free 2-row LDS write.
#pragma unroll
    for (int t = 0; t < 16; t += 2) {
        v4i a_[2], b_[2];
#pragma unroll
        for (int j = 0; j < 2; ++j) {
            const int G = (t + j) * 256 + tid;
            a_[j] = *((const v4i*)Ap + G);
            b_[j] = *((const v4i*)Bp + G);
        }
#pragma unroll
        for (int j = 0; j < 2; ++j) {
            const int G = (t + j) * 256 + tid;
            const int m = G >> 5;
            const int q = G & 31;
            const int loff = m * 128 + (((q >> 2) ^ (m & 7)) << 4) + ((q & 3) << 2);
            *(int*)(Als + loff) = pack4(a_[j]);
            *(int*)(Bls + loff) = pack4(b_[j]);
        }
    }
    lgkm_barrier();

    // ---- Compute: wave w -> cols w*32..+31, all 128 rows; 4 K-steps of 32.
    v16i acc[4] = {};
#pragma unroll
    for (int kk = 0; kk < 4; ++kk) {
        const int g = kk * 2 + half_;
        const int n = wave * 32 + lrow;
        const v4i bf = *(const v4i*)(Bls + n * 128 + ((g ^ (n & 7)) << 4));
        v4i af[4];
#pragma unroll
        for (int mi = 0; mi < 4; ++mi) {
            const int m = mi * 32 + lrow;
            af[mi] = *(const v4i*)(Als + m * 128 + ((g ^ (m & 7)) << 4));
        }
#pragma unroll
        for (int mi = 0; mi < 4; ++mi)
            acc[mi] = __builtin_amdgcn_mfma_i32_32x32x32_i8(af[mi], bf, acc[mi], 0, 0, 0);
    }
    lgkm_barrier();   // all fragment ds_reads done before LDS slab reuse

    // ---- Epilogue: 2 rounds of 64-row LDS transpose (full 32 KB slab) ->
    //      512B-per-half-wave plain dwordx4 stores.  No vmcnt drain anywhere.
    //      C/D layout: col=lane&31, row=(r&3)+8*(r>>2)+4*(lane>>5).
    int* chunk = (int*)smem;           // 64 x 128 int32 slab
    int* outb  = out + ((size_t)bz << 20) + n0;

#pragma unroll
    for (int J = 0; J < 2; ++J) {
#pragma unroll
        for (int q = 0; q < 2; ++q) {
#pragma unroll
            for (int r = 0; r < 16; ++r) {
                const int row_local = q * 32 + (r & 3) + 8 * (r >> 2) + 4 * half_;
                chunk[row_local * 128 + wave * 32 + lrow] =
                    __float2int_rn((float)acc[2 * J + q][r] * alpha);
            }
        }
        lgkm_barrier();                // slab filled (lgkm only)
#pragma unroll
        for (int p = 0; p < 8; ++p) {
            const int row_local = p * 8 + (tid >> 5);       // 0..63
            const v4i v = *(const v4i*)((const uint8_t*)chunk + p * 4096 + tid * 16);
            *(v4i*)(outb + (size_t)(m0 + J * 64 + row_local) * 1024 + (tid & 31) * 4) = v;
        }
        if (J == 0) lgkm_barrier();    // slab reads done before round-1 writes
    }
}

extern "C" void kernel_launch(void* const* d_in, const int* in_sizes, int n_in,
                              void* d_out, int out_size, void* d_ws, size_t ws_size,
                              hipStream_t stream) {
    const int*   A     = (const int*)d_in[0];
    const int*   Bm    = (const int*)d_in[1];
    const float* alpha = (const float*)d_in[2];
    int*         out   = (int*)d_out;
    (void)d_ws; (void)ws_size;   // workspace intentionally unused (R7 probe)

    dim3 grid(8, 8, 64);   // n-tiles, m-tiles, batch
    bmm_s8s8_s32_fused<<<grid, dim3(256), 0, stream>>>(A, Bm, alpha, out);
}

// Round 4
// 324.033 us; speedup vs baseline: 1.0569x; 1.0569x over previous
//
#include <hip/hip_runtime.h>
#include <stdint.h>

// BMM: out[b,m,n] = round(alpha * sum_k a[b,m,k]*b[b,n,k]), int8 x int8 -> int32
// B=64, M=1024, N=1024, K=128.  Inputs arrive int32-expanded; output 256 MB int32.
//
// R8 = best-of-session recombination.  Session facts:
//  - R7 proved the 1 GiB harness poison fill (~167us) is unconditional (fixed).
//  - R7 fused (no prepack) = 342.5us: direct int32 reads cost ~+15us vs the
//    prepack path -> two-pass structure restored.
//  - R4 (NT stores, 4-round epilogue, __syncthreads) = 322.8;
//    R6 (plain stores, 2-round epilogue, lgkm barriers) = 327.9.  Confounded;
//    theory favors NT stores (256 MiB write-allocate would thrash the 4 MiB
//    per-XCD L2 holding the packed panels) and favors fewer barriers.
//  R8 = prepack + NT epilogue stores + lgkm-only barriers + 2-round 64-row
//  epilogue + hoisted staging loads.
//
// Calibrated model: fixed harness stream ~265us; our floor = prepack 13us +
// BMM write floor ~45us.  R4's 322.8 sits at that floor -> if R8 lands
// ~318-325 this problem is at its roofline.

typedef int v4i  __attribute__((ext_vector_type(4)));
typedef int v16i __attribute__((ext_vector_type(16)));

__device__ __forceinline__ int pack4(v4i w) {
    // low bytes of 4 int32 -> one dword of 4 int8 (two's complement)
    return (w.x & 0xFF) | ((w.y & 0xFF) << 8) | ((w.z & 0xFF) << 16) | (w.w << 24);
}

// Raw barrier: lgkm-only wait, NO vmcnt drain (unlike __syncthreads()).
// Correct here: barriers only order LDS producer/consumer phases; global
// stores are never read back.
__device__ __forceinline__ void lgkm_barrier() {
    asm volatile("s_waitcnt lgkmcnt(0)" ::: "memory");
    __builtin_amdgcn_s_barrier();
}

// ---- Pass 1: int32-expanded -> packed int8. 8.39M elems per tensor,
//      16 elems/thread, 2048 blocks x 256 threads.
__global__ __launch_bounds__(256) void prepack_kernel(
    const int* __restrict__ A, const int* __restrict__ Bm,
    uint8_t* __restrict__ Apk, uint8_t* __restrict__ Bpk)
{
    const int g = blockIdx.x * 256 + threadIdx.x;   // granule 0..524287
    const size_t eoff = (size_t)g * 16;             // int32 element offset

    v4i a[4], b[4];
#pragma unroll
    for (int i = 0; i < 4; ++i) {
        a[i] = __builtin_nontemporal_load((const v4i*)(A + eoff) + i);
        b[i] = __builtin_nontemporal_load((const v4i*)(Bm + eoff) + i);
    }
    v4i pa = { pack4(a[0]), pack4(a[1]), pack4(a[2]), pack4(a[3]) };
    v4i pb = { pack4(b[0]), pack4(b[1]), pack4(b[2]), pack4(b[3]) };
    *(v4i*)(Apk + eoff) = pa;   // plain stores: packed set is re-read 8x by BMM
    *(v4i*)(Bpk + eoff) = pb;
}

// ---- Pass 2: GEMM on packed int8. One 128x128 C-tile per block.
__global__ __launch_bounds__(256, 4) void bmm_s8s8_s32_kernel(
    const uint8_t* __restrict__ Apk,   // [64,1024,128] int8
    const uint8_t* __restrict__ Bpk,   // [64,1024,128] int8
    const float*   __restrict__ alpha_p,
    int*           __restrict__ out)   // [64,1024,1024]
{
    __shared__ uint8_t smem[32768];
    uint8_t* Als = smem;               // 16 KB, XOR-swizzled rows
    uint8_t* Bls = smem + 16384;       // 16 KB

    const int tid   = threadIdx.x;
    const int lane  = tid & 63;
    const int wave  = tid >> 6;        // 0..3
    const int half_ = lane >> 5;       // 0..1
    const int lrow  = lane & 31;       // 0..31

    const int bz = blockIdx.z;
    const int m0 = blockIdx.y << 7;
    const int n0 = blockIdx.x << 7;

    const float alpha = *alpha_p;

    // Packed tile bases (bytes); each 128-row tile is 16 KB contiguous.
    const size_t abase = ((size_t)bz * 1024 + (size_t)m0) * 128;
    const size_t bbase = ((size_t)bz * 1024 + (size_t)n0) * 128;

    // ---- Stage: 4 granules (16 B) per thread per matrix.  All 8 global
    //      loads issued first (ILP), then swizzled ds_writes:
    //      LDS[m][gp^(m&7)] = tile[m][gp].
    v4i pa[4], pb[4];
#pragma unroll
    for (int t = 0; t < 4; ++t) {
        const int G = t * 256 + tid;               // granule 0..1023
        pa[t] = *(const v4i*)(Apk + abase + (size_t)G * 16);
        pb[t] = *(const v4i*)(Bpk + bbase + (size_t)G * 16);
    }
#pragma unroll
    for (int t = 0; t < 4; ++t) {
        const int G  = t * 256 + tid;
        const int m  = G >> 3;
        const int gp = G & 7;
        const int loff = m * 128 + ((gp ^ (m & 7)) << 4);
        *(v4i*)(Als + loff) = pa[t];
        *(v4i*)(Bls + loff) = pb[t];
    }
    lgkm_barrier();

    // ---- Compute: wave w -> cols w*32..+31, all 128 rows; 4 K-steps of 32.
    v16i acc[4] = {};
#pragma unroll
    for (int kk = 0; kk < 4; ++kk) {
        const int g = kk * 2 + half_;
        const int n = wave * 32 + lrow;
        const v4i bf = *(const v4i*)(Bls + n * 128 + ((g ^ (n & 7)) << 4));
        v4i af[4];
#pragma unroll
        for (int mi = 0; mi < 4; ++mi) {
            const int m = mi * 32 + lrow;
            af[mi] = *(const v4i*)(Als + m * 128 + ((g ^ (m & 7)) << 4));
        }
#pragma unroll
        for (int mi = 0; mi < 4; ++mi)
            acc[mi] = __builtin_amdgcn_mfma_i32_32x32x32_i8(af[mi], bf, acc[mi], 0, 0, 0);
    }
    lgkm_barrier();   // all fragment ds_reads done before LDS slab reuse

    // ---- Epilogue: 2 rounds of 64-row LDS transpose (full 32 KB slab) ->
    //      512B-per-half-wave NONTEMPORAL dwordx4 stores (protect per-XCD L2
    //      from 256 MiB write-allocate thrash of the packed panels).
    //      No vmcnt drain anywhere: stores stay in flight until s_endpgm.
    //      C/D layout: col=lane&31, row=(r&3)+8*(r>>2)+4*(lane>>5).
    int* chunk = (int*)smem;           // 64 x 128 int32 slab
    int* outb  = out + ((size_t)bz << 20) + n0;

#pragma unroll
    for (int J = 0; J < 2; ++J) {
#pragma unroll
        for (int q = 0; q < 2; ++q) {
#pragma unroll
            for (int r = 0; r < 16; ++r) {
                const int row_local = q * 32 + (r & 3) + 8 * (r >> 2) + 4 * half_;
                chunk[row_local * 128 + wave * 32 + lrow] =
                    __float2int_rn((float)acc[2 * J + q][r] * alpha);
            }
        }
        lgkm_barrier();                // slab filled (lgkm only)
#pragma unroll
        for (int p = 0; p < 8; ++p) {
            const int row_local = p * 8 + (tid >> 5);       // 0..63
            const v4i v = *(const v4i*)((const uint8_t*)chunk + p * 4096 + tid * 16);
            __builtin_nontemporal_store(
                v, (v4i*)(outb + (size_t)(m0 + J * 64 + row_local) * 1024 + (tid & 31) * 4));
        }
        if (J == 0) lgkm_barrier();    // slab reads done before round-1 writes
    }
}

extern "C" void kernel_launch(void* const* d_in, const int* in_sizes, int n_in,
                              void* d_out, int out_size, void* d_ws, size_t ws_size,
                              hipStream_t stream) {
    const int*   A     = (const int*)d_in[0];
    const int*   Bm    = (const int*)d_in[1];
    const float* alpha = (const float*)d_in[2];
    int*         out   = (int*)d_out;

    uint8_t* Apk = (uint8_t*)d_ws;                 // 8,388,608 B
    uint8_t* Bpk = (uint8_t*)d_ws + (8u << 20);    // 8,388,608 B

    prepack_kernel<<<dim3(2048), dim3(256), 0, stream>>>(A, Bm, Apk, Bpk);

    dim3 grid(8, 8, 64);   // n-tiles, m-tiles, batch
    bmm_s8s8_s32_kernel<<<grid, dim3(256), 0, stream>>>(Apk, Bpk, alpha, out);
}